// Round 4
// baseline (739.472 us; speedup 1.0000x reference)
//
#include <hip/hip_runtime.h>

// Self-attention forward. Inputs f32: x[4,2048,1024], Wqkv[1024,3072],
// bqkv[3072], Wout[1024,1024], bout[1024]; mask[4,2048,2048] int32.
// Output f32 [4,2048,1024]. Internals: bf16 MFMA GEMMs, f32 accumulate.

typedef __attribute__((ext_vector_type(8))) short short8;
typedef __attribute__((ext_vector_type(4))) float f32x4;
typedef unsigned short u16;

#define SEQ 2048
#define NB 4

static __device__ __forceinline__ u16 f2bf(float f) {
    unsigned int u = __builtin_bit_cast(unsigned int, f);
    u += 0x7fffu + ((u >> 16) & 1u);   // RNE
    return (u16)(u >> 16);
}
static __device__ __forceinline__ float bf2f(u16 h) {
    unsigned int u = ((unsigned int)h) << 16;
    return __builtin_bit_cast(float, u);
}

// f32 -> bf16, 8 elems/thread.
__global__ __launch_bounds__(256) void cvt_bf16(const float* __restrict__ s,
                                                u16* __restrict__ d, long n) {
    long i = ((long)blockIdx.x * 256 + threadIdx.x) * 8;
    if (i >= n) return;
    f32x4 a = *(const f32x4*)(s + i);
    f32x4 b = *(const f32x4*)(s + i + 4);
    short8 o;
    o[0] = (short)f2bf(a.x); o[1] = (short)f2bf(a.y);
    o[2] = (short)f2bf(a.z); o[3] = (short)f2bf(a.w);
    o[4] = (short)f2bf(b.x); o[5] = (short)f2bf(b.y);
    o[6] = (short)f2bf(b.z); o[7] = (short)f2bf(b.w);
    *(short8*)(d + i) = o;
}

// bf16 MFMA GEMM, BM=BN=64, BK=32, 4 waves, mfma_f32_16x16x32_bf16.
// C[m][n] = sum_k A[m][k]*Bhat[n][k]; BTRANS ? Bhat=B rows : Bhat=B^T.
// (Cross-validated vs an independent VALU GEMM in rounds 2/3: identical output.)
// EPI 0: bf16 out + optional f32 bias.
// EPI 1: bf16 out, *scale, mask==0 -> 1e-10.
// EPI 2: f32 out + f32 bias.
template<bool BTRANS, int EPI>
__global__ __launch_bounds__(256) void gemm64(
    const u16* __restrict__ Ap, long lda, long aBatch,
    const u16* __restrict__ Bp, long ldb, long bBatch,
    void* __restrict__ Cp, long ldc, long cBatch,
    const float* __restrict__ bias,
    const int* __restrict__ mask, long maskBatch,
    float scale, int K)
{
    __shared__ __attribute__((aligned(16))) u16 As[64][40];
    __shared__ __attribute__((aligned(16))) u16 Bs[64][40];

    const int tid = threadIdx.x;
    const int b = blockIdx.z;
    const long m0 = (long)blockIdx.y * 64;
    const long n0 = (long)blockIdx.x * 64;

    const u16* A = Ap + (long)b * aBatch;
    const u16* B = Bp + (long)b * bBatch;

    const int lane = tid & 63;
    const int wave = tid >> 6;
    const int m16 = lane & 15;
    const int quad = lane >> 4;

    f32x4 acc[4];
    #pragma unroll
    for (int t = 0; t < 4; t++) acc[t] = (f32x4){0.f, 0.f, 0.f, 0.f};

    for (int k0 = 0; k0 < K; k0 += 32) {
        {   // A tile: As[r][kk] = A[m0+r][k0+kk]
            const int r = tid >> 2, kq = tid & 3;
            *(uint4*)&As[r][kq * 8] = *(const uint4*)(A + (m0 + r) * lda + k0 + kq * 8);
        }
        if (BTRANS) {   // Bs[n][kk] = B[n0+n][k0+kk]
            const int n = tid >> 2, kq = tid & 3;
            *(uint4*)&Bs[n][kq * 8] = *(const uint4*)(B + (n0 + n) * ldb + k0 + kq * 8);
        } else {        // Bs[n][kk] = B[k0+kk][n0+n]
            const int kr = tid >> 3, nc = tid & 7;
            uint4 v = *(const uint4*)(B + (long)(k0 + kr) * ldb + n0 + nc * 8);
            const u16* e = (const u16*)&v;
            #pragma unroll
            for (int j = 0; j < 8; j++) Bs[nc * 8 + j][kr] = e[j];
        }
        __syncthreads();

        const short8 a = *(const short8*)&As[wave * 16 + m16][quad * 8];
        #pragma unroll
        for (int t = 0; t < 4; t++) {
            const short8 bb = *(const short8*)&Bs[t * 16 + m16][quad * 8];
            acc[t] = __builtin_amdgcn_mfma_f32_16x16x32_bf16(a, bb, acc[t], 0, 0, 0);
        }
        __syncthreads();
    }

    // D mapping: col = lane&15 (+16t), row = quad*4 + r  (verified m89/m91)
    const long row0 = m0 + wave * 16 + quad * 4;
    if (EPI == 0 || EPI == 1) {
        u16* C = (u16*)Cp + (long)b * cBatch;
        if (EPI == 0) {
            #pragma unroll
            for (int t = 0; t < 4; t++) {
                const long col = n0 + t * 16 + m16;
                const float bv = bias ? bias[col] : 0.f;
                #pragma unroll
                for (int r = 0; r < 4; r++)
                    C[(row0 + r) * ldc + col] = f2bf(acc[t][r] + bv);
            }
        } else {
            const int* mb = mask + (long)b * maskBatch;
            #pragma unroll
            for (int t = 0; t < 4; t++) {
                const long col = n0 + t * 16 + m16;
                #pragma unroll
                for (int r = 0; r < 4; r++) {
                    const float s = acc[t][r] * scale;
                    const int mv = mb[(row0 + r) * SEQ + col];
                    C[(row0 + r) * ldc + col] = f2bf((mv == 0) ? 1e-10f : s);
                }
            }
        }
    } else {
        float* C = (float*)Cp + (long)b * cBatch;
        #pragma unroll
        for (int t = 0; t < 4; t++) {
            const long col = n0 + t * 16 + m16;
            const float bv = bias ? bias[col] : 0.f;
            #pragma unroll
            for (int r = 0; r < 4; r++)
                C[(row0 + r) * ldc + col] = acc[t][r] + bv;
        }
    }
}

// in-place row softmax over 2048 bf16 (f32 math). 1 block (4 waves) per row.
__global__ __launch_bounds__(256) void softmax2048(u16* __restrict__ S) {
    u16* p = S + (long)blockIdx.x * SEQ;
    const int tid = threadIdx.x;

    short8 v = *(const short8*)(p + tid * 8);
    float f[8];
    #pragma unroll
    for (int j = 0; j < 8; j++) f[j] = bf2f((u16)v[j]);

    float m = f[0];
    #pragma unroll
    for (int j = 1; j < 8; j++) m = fmaxf(m, f[j]);
    #pragma unroll
    for (int i = 1; i < 64; i <<= 1) m = fmaxf(m, __shfl_xor(m, i));

    __shared__ float redm[4], reds[4];
    if ((tid & 63) == 0) redm[tid >> 6] = m;
    __syncthreads();
    m = fmaxf(fmaxf(redm[0], redm[1]), fmaxf(redm[2], redm[3]));

    float e[8], s = 0.f;
    #pragma unroll
    for (int j = 0; j < 8; j++) { e[j] = __expf(f[j] - m); s += e[j]; }
    #pragma unroll
    for (int i = 1; i < 64; i <<= 1) s += __shfl_xor(s, i);
    if ((tid & 63) == 0) reds[tid >> 6] = s;
    __syncthreads();
    s = reds[0] + reds[1] + reds[2] + reds[3];

    const float inv = 1.f / s;
    short8 o;
    #pragma unroll
    for (int j = 0; j < 8; j++) o[j] = (short)f2bf(e[j] * inv);
    *(short8*)(p + tid * 8) = o;
}

extern "C" void kernel_launch(void* const* d_in, const int* in_sizes, int n_in,
                              void* d_out, int out_size, void* d_ws, size_t ws_size,
                              hipStream_t stream) {
    const float* x    = (const float*)d_in[0];
    const int*   mask = (const int*)d_in[1];
    const float* Wqkv = (const float*)d_in[2];
    const float* bqkv = (const float*)d_in[3];
    const float* Wout = (const float*)d_in[4];
    const float* bout = (const float*)d_in[5];
    float* out = (float*)d_out;

    char* ws = (char*)d_ws;
    // ws layout with lifetime overlap — total 102,760,448 bytes (~98 MB):
    //   [0,        50331648) qkv  bf16 [8192][3072]          (K1 -> K4)
    //   [50331648, 67108864) wqh  bf16 (cvt -> K1), then attn bf16 (K4 -> K5)
    //   [67108864, 69206016) woh  bf16                        (cvt -> K5)
    //   [69206016,102760448) xh   bf16 (cvt -> K1), then sc bf16 [4][2048][2048] (K2 -> K4)
    u16* qkv  = (u16*)(ws + 0);
    u16* wqh  = (u16*)(ws + 50331648);
    u16* attn = (u16*)(ws + 50331648);
    u16* woh  = (u16*)(ws + 67108864);
    u16* xh   = (u16*)(ws + 69206016);
    u16* sc   = (u16*)(ws + 69206016);

    cvt_bf16<<<4096, 256, 0, stream>>>(x,    xh,  8388608);
    cvt_bf16<<<1536, 256, 0, stream>>>(Wqkv, wqh, 3145728);
    cvt_bf16<<< 512, 256, 0, stream>>>(Wout, woh, 1048576);

    // K1: qkv = x @ Wqkv + bqkv        (M=8192, N=3072, K=1024), bf16 out
    gemm64<false, 0><<<dim3(48, 128, 1), 256, 0, stream>>>(
        xh, 1024, 0, wqh, 3072, 0, qkv, 3072, 0, bqkv, nullptr, 0, 1.f, 1024);

    // K2: sc[b] = (Q[b] @ K[b]^T)/32, mask==0 -> 1e-10   (M=N=2048, K=1024)
    gemm64<true, 1><<<dim3(32, 32, NB), 256, 0, stream>>>(
        qkv, 3072, (long)SEQ * 3072, qkv + 1024, 3072, (long)SEQ * 3072,
        sc, SEQ, (long)SEQ * SEQ, nullptr, mask, (long)SEQ * SEQ, 0.03125f, 1024);

    // K3: softmax rows (f32 math, bf16 storage)
    softmax2048<<<dim3(NB * SEQ), 256, 0, stream>>>(sc);

    // K4: attn[b] = P[b] @ V[b]        (M=2048, N=1024, K=2048), bf16 out
    gemm64<false, 0><<<dim3(16, 32, NB), 256, 0, stream>>>(
        sc, SEQ, (long)SEQ * SEQ, qkv + 2048, 3072, (long)SEQ * 3072,
        attn, 1024, (long)SEQ * 1024, nullptr, nullptr, 0, 1.f, 2048);

    // K5: out = attn @ Wout + bout     (M=8192, N=1024, K=1024), f32 out
    gemm64<false, 2><<<dim3(16, 128, 1), 256, 0, stream>>>(
        attn, 1024, 0, woh, 1024, 0, out, 1024, 0, bout, nullptr, 0, 1.f, 1024);
}

// Round 5
// 400.136 us; speedup vs baseline: 1.8480x; 1.8480x over previous
//
#include <hip/hip_runtime.h>

// Self-attention forward. Inputs f32: x[4,2048,1024], Wqkv[1024,3072],
// bqkv[3072], Wout[1024,1024], bout[1024]; mask[4,2048,2048] int32.
// Output f32 [4,2048,1024]. Internals: bf16 MFMA GEMMs (m97-style 128x128
// tile, BK=32, global_load_lds width-16 staging), f32 accumulate.
// All GEMM B-operands are pre-transposed [N][K] so staging is pure
// vector loads (round-4's 1.1e8 LDS bank conflicts came from the
// scalar-scatter B-transpose path: nc*160 = 0 mod 128 bytes -> 16-way).

typedef __attribute__((ext_vector_type(8))) short short8;
typedef __attribute__((ext_vector_type(4))) float f32x4;
typedef unsigned short u16;

#define SEQ 2048
#define NB 4

static __device__ __forceinline__ u16 f2bf(float f) {
    unsigned int u = __builtin_bit_cast(unsigned int, f);
    u += 0x7fffu + ((u >> 16) & 1u);   // RNE
    return (u16)(u >> 16);
}
static __device__ __forceinline__ float bf2f(u16 h) {
    unsigned int u = ((unsigned int)h) << 16;
    return __builtin_bit_cast(float, u);
}

// async global->LDS, 16 bytes/lane. LDS dest = wave-uniform base + lane*16.
static __device__ __forceinline__ void gld16(u16* l, const u16* g) {
    __builtin_amdgcn_global_load_lds(
        (__attribute__((address_space(1))) void*)(g),
        (__attribute__((address_space(3))) void*)(l),
        16, 0, 0);
}

// f32 -> bf16, 8 elems/thread.
__global__ __launch_bounds__(256) void cvt_bf16(const float* __restrict__ s,
                                                u16* __restrict__ d, long n) {
    long i = ((long)blockIdx.x * 256 + threadIdx.x) * 8;
    if (i >= n) return;
    f32x4 a = *(const f32x4*)(s + i);
    f32x4 b = *(const f32x4*)(s + i + 4);
    short8 o;
    o[0] = (short)f2bf(a.x); o[1] = (short)f2bf(a.y);
    o[2] = (short)f2bf(a.z); o[3] = (short)f2bf(a.w);
    o[4] = (short)f2bf(b.x); o[5] = (short)f2bf(b.y);
    o[6] = (short)f2bf(b.z); o[7] = (short)f2bf(b.w);
    *(short8*)(d + i) = o;
}

// f32 [R][C] -> bf16 [C][R] (transpose + convert), 32x32 LDS tiles.
__global__ __launch_bounds__(256) void transpose_cvt(const float* __restrict__ in,
                                                     u16* __restrict__ out,
                                                     int R, int C) {
    __shared__ float t[32][33];
    const int c0 = blockIdx.x * 32;
    const int r0 = blockIdx.y * 32;
    const int x = threadIdx.x & 31;
    const int y = (threadIdx.x >> 5) * 4;
    #pragma unroll
    for (int i = 0; i < 4; i++)
        t[y + i][x] = in[(long)(r0 + y + i) * C + c0 + x];
    __syncthreads();
    #pragma unroll
    for (int i = 0; i < 4; i++)
        out[(long)(c0 + y + i) * R + r0 + x] = f2bf(t[x][y + i]);
}

// V slice of qkv (per batch [2048 s][1024 d], row stride 3072, col offset 2048)
// -> vt [b][1024 d][2048 s]. bf16 32x32 tile transpose.
__global__ __launch_bounds__(256) void transpose_v(const u16* __restrict__ qkv,
                                                   u16* __restrict__ vt) {
    __shared__ u16 t[32][33];
    const int b = blockIdx.z;
    const int s0 = blockIdx.y * 32;
    const int d0 = blockIdx.x * 32;
    const int x = threadIdx.x & 31;
    const int y = (threadIdx.x >> 5) * 4;
    const u16* src = qkv + (long)b * SEQ * 3072 + 2048;
    u16* dst = vt + (long)b * 1024 * SEQ;
    #pragma unroll
    for (int i = 0; i < 4; i++)
        t[y + i][x] = src[(long)(s0 + y + i) * 3072 + d0 + x];
    __syncthreads();
    #pragma unroll
    for (int i = 0; i < 4; i++)
        dst[(long)(d0 + y + i) * SEQ + s0 + x] = t[x][y + i];
}

// m97-style bf16 MFMA GEMM. BM=BN=128, BK=32, 256 threads = 4 waves,
// wave (wm,wn) owns a 64x64 patch = 4x4 frags of mfma_f32_16x16x32_bf16.
// C[m][n] = sum_k A[m][k] * Bt[n][k]   (Bt is B^T, [N][K] row-major).
// Staging: 4 global_load_lds(16B) per thread per K-step into unpadded
// As[128][32] / Bs[128][32] (lane-ordered, as the instruction requires).
// EPI 0: bf16 out + optional f32 bias.
// EPI 1: bf16 out, *scale, mask==0 -> 1e-10.
// EPI 2: f32 out + f32 bias.
template<int EPI>
__global__ __launch_bounds__(256) void gemm128(
    const u16* __restrict__ Ap, long lda, long aBatch,
    const u16* __restrict__ Bp, long ldb, long bBatch,
    void* __restrict__ Cp, long ldc, long cBatch,
    const float* __restrict__ bias,
    const int* __restrict__ mask, long maskBatch,
    float scale, int K)
{
    __shared__ __attribute__((aligned(16))) u16 As[128 * 32];
    __shared__ __attribute__((aligned(16))) u16 Bs[128 * 32];

    const int tid = threadIdx.x;
    const int lane = tid & 63;
    const int wave = tid >> 6;
    const int b = blockIdx.z;
    const long m0 = (long)blockIdx.y * 128;
    const long n0 = (long)blockIdx.x * 128;

    const u16* A = Ap + (long)b * aBatch;
    const u16* B = Bp + (long)b * bBatch;

    const int wm = (wave >> 1) * 64;      // wave row offset in tile
    const int wn = (wave & 1) * 64;       // wave col offset in tile
    const int m16 = lane & 15;
    const int quad = lane >> 4;

    // staging coords: this wave's 2 chunks cover rows [wave*32, wave*32+32)
    const int srow = wave * 32 + (lane >> 2);   // +0 / +16 for the two chunks
    const int skk = (lane & 3) * 8;

    f32x4 acc[4][4];
    #pragma unroll
    for (int mi = 0; mi < 4; mi++)
        #pragma unroll
        for (int ni = 0; ni < 4; ni++)
            acc[mi][ni] = (f32x4){0.f, 0.f, 0.f, 0.f};

    for (int k0 = 0; k0 < K; k0 += 32) {
        gld16(As + wave * 1024,       A + (m0 + srow) * lda + k0 + skk);
        gld16(As + wave * 1024 + 512, A + (m0 + srow + 16) * lda + k0 + skk);
        gld16(Bs + wave * 1024,       B + (n0 + srow) * ldb + k0 + skk);
        gld16(Bs + wave * 1024 + 512, B + (n0 + srow + 16) * ldb + k0 + skk);
        __syncthreads();   // compiler emits s_waitcnt vmcnt(0) before s_barrier

        short8 af[4], bf[4];
        #pragma unroll
        for (int i = 0; i < 4; i++) {
            af[i] = *(const short8*)&As[(wm + i * 16 + m16) * 32 + quad * 8];
            bf[i] = *(const short8*)&Bs[(wn + i * 16 + m16) * 32 + quad * 8];
        }
        #pragma unroll
        for (int mi = 0; mi < 4; mi++)
            #pragma unroll
            for (int ni = 0; ni < 4; ni++)
                acc[mi][ni] = __builtin_amdgcn_mfma_f32_16x16x32_bf16(
                    af[mi], bf[ni], acc[mi][ni], 0, 0, 0);
        __syncthreads();
    }

    // D mapping: col = lane&15 (+16*ni), row = quad*4 + r (+16*mi)
    const long row_base = m0 + wm + quad * 4;
    if (EPI == 0) {
        u16* C = (u16*)Cp + (long)b * cBatch;
        #pragma unroll
        for (int ni = 0; ni < 4; ni++) {
            const long col = n0 + wn + ni * 16 + m16;
            const float bv = bias ? bias[col] : 0.f;
            #pragma unroll
            for (int mi = 0; mi < 4; mi++)
                #pragma unroll
                for (int r = 0; r < 4; r++)
                    C[(row_base + mi * 16 + r) * ldc + col] = f2bf(acc[mi][ni][r] + bv);
        }
    } else if (EPI == 1) {
        u16* C = (u16*)Cp + (long)b * cBatch;
        const int* mb = mask + (long)b * maskBatch;
        #pragma unroll
        for (int ni = 0; ni < 4; ni++) {
            const long col = n0 + wn + ni * 16 + m16;
            #pragma unroll
            for (int mi = 0; mi < 4; mi++)
                #pragma unroll
                for (int r = 0; r < 4; r++) {
                    const long row = row_base + mi * 16 + r;
                    const float s = acc[mi][ni][r] * scale;
                    const int mv = mb[row * SEQ + col];
                    C[row * ldc + col] = f2bf((mv == 0) ? 1e-10f : s);
                }
        }
    } else {
        float* C = (float*)Cp + (long)b * cBatch;
        #pragma unroll
        for (int ni = 0; ni < 4; ni++) {
            const long col = n0 + wn + ni * 16 + m16;
            const float bv = bias ? bias[col] : 0.f;
            #pragma unroll
            for (int mi = 0; mi < 4; mi++)
                #pragma unroll
                for (int r = 0; r < 4; r++)
                    C[(row_base + mi * 16 + r) * ldc + col] = acc[mi][ni][r] + bv;
        }
    }
}

// in-place row softmax over 2048 bf16 (f32 math). 1 block (4 waves) per row.
__global__ __launch_bounds__(256) void softmax2048(u16* __restrict__ S) {
    u16* p = S + (long)blockIdx.x * SEQ;
    const int tid = threadIdx.x;

    short8 v = *(const short8*)(p + tid * 8);
    float f[8];
    #pragma unroll
    for (int j = 0; j < 8; j++) f[j] = bf2f((u16)v[j]);

    float m = f[0];
    #pragma unroll
    for (int j = 1; j < 8; j++) m = fmaxf(m, f[j]);
    #pragma unroll
    for (int i = 1; i < 64; i <<= 1) m = fmaxf(m, __shfl_xor(m, i));

    __shared__ float redm[4], reds[4];
    if ((tid & 63) == 0) redm[tid >> 6] = m;
    __syncthreads();
    m = fmaxf(fmaxf(redm[0], redm[1]), fmaxf(redm[2], redm[3]));

    float e[8], s = 0.f;
    #pragma unroll
    for (int j = 0; j < 8; j++) { e[j] = __expf(f[j] - m); s += e[j]; }
    #pragma unroll
    for (int i = 1; i < 64; i <<= 1) s += __shfl_xor(s, i);
    if ((tid & 63) == 0) reds[tid >> 6] = s;
    __syncthreads();
    s = reds[0] + reds[1] + reds[2] + reds[3];

    const float inv = 1.f / s;
    short8 o;
    #pragma unroll
    for (int j = 0; j < 8; j++) o[j] = (short)f2bf(e[j] * inv);
    *(short8*)(p + tid * 8) = o;
}

extern "C" void kernel_launch(void* const* d_in, const int* in_sizes, int n_in,
                              void* d_out, int out_size, void* d_ws, size_t ws_size,
                              hipStream_t stream) {
    const float* x    = (const float*)d_in[0];
    const int*   mask = (const int*)d_in[1];
    const float* Wqkv = (const float*)d_in[2];
    const float* bqkv = (const float*)d_in[3];
    const float* Wout = (const float*)d_in[4];
    const float* bout = (const float*)d_in[5];
    float* out = (float*)d_out;

    char* ws = (char*)d_ws;
    // ws layout, total 102,760,448 bytes (same footprint as the passing round):
    //   [0,        16777216) xh  bf16 [8192][1024]          (cvt -> K1)
    //   [16777216, 23068672) wqt bf16 [3072][1024]          (cvt -> K1)
    //   [0,        33554432) sc  bf16 [4][2048][2048]       (K2 -> K4; xh,wqt dead)
    //   [33554432, 35651584) wot bf16 [1024][1024]          (cvt -> K5)
    //   [35651584, 85983232) qkv bf16 [8192][3072]          (K1 -> K2)
    //   [35651584, 52428800) attn bf16 [8192][1024]         (K4 -> K5; qkv dead)
    //   [85983232,102760448) vt  bf16 [4][1024][2048]       (transpose_v -> K4)
    u16* xh   = (u16*)(ws + 0);
    u16* wqt  = (u16*)(ws + 16777216);
    u16* sc   = (u16*)(ws + 0);
    u16* wot  = (u16*)(ws + 33554432);
    u16* qkv  = (u16*)(ws + 35651584);
    u16* attn = (u16*)(ws + 35651584);
    u16* vt   = (u16*)(ws + 85983232);

    cvt_bf16<<<4096, 256, 0, stream>>>(x, xh, 8388608);
    transpose_cvt<<<dim3(96, 32), 256, 0, stream>>>(Wqkv, wqt, 1024, 3072);
    transpose_cvt<<<dim3(32, 32), 256, 0, stream>>>(Wout, wot, 1024, 1024);

    // K1: qkv = x @ Wqkv + bqkv   (M=8192, N=3072, K=1024), bf16 out
    gemm128<0><<<dim3(24, 64, 1), 256, 0, stream>>>(
        xh, 1024, 0, wqt, 1024, 0, qkv, 3072, 0, bqkv, nullptr, 0, 1.f, 1024);

    // V slice -> vt [b][d][s]
    transpose_v<<<dim3(32, 64, NB), 256, 0, stream>>>(qkv, vt);

    // K2: sc[b] = (Q[b] @ K[b]^T)/32, mask==0 -> 1e-10   (M=N=2048, K=1024)
    gemm128<1><<<dim3(16, 16, NB), 256, 0, stream>>>(
        qkv, 3072, (long)SEQ * 3072, qkv + 1024, 3072, (long)SEQ * 3072,
        sc, SEQ, (long)SEQ * SEQ, nullptr, mask, (long)SEQ * SEQ, 0.03125f, 1024);

    // K3: softmax rows (f32 math, bf16 storage)
    softmax2048<<<dim3(NB * SEQ), 256, 0, stream>>>(sc);

    // K4: attn[b] = P[b] @ V[b]   (M=2048, N=1024, K=2048), bf16 out
    gemm128<0><<<dim3(8, 16, NB), 256, 0, stream>>>(
        sc, SEQ, (long)SEQ * SEQ, vt, SEQ, (long)1024 * SEQ,
        attn, 1024, (long)SEQ * 1024, nullptr, nullptr, 0, 1.f, 2048);

    // K5: out = attn @ Wout + bout   (M=8192, N=1024, K=1024), f32 out
    gemm128<2><<<dim3(8, 64, 1), 256, 0, stream>>>(
        attn, 1024, 0, wot, 1024, 0, out, 1024, 0, bout, nullptr, 0, 1.f, 1024);
}

// Round 6
// 392.173 us; speedup vs baseline: 1.8856x; 1.0203x over previous
//
#include <hip/hip_runtime.h>

// Self-attention forward. Inputs f32: x[4,2048,1024], Wqkv[1024,3072],
// bqkv[3072], Wout[1024,1024], bout[1024]; mask[4,2048,2048] int32.
// Output f32 [4,2048,1024]. Internals: bf16 MFMA GEMMs (128x128 tile,
// BK=64 — 32 MFMA per barrier-pair to halve the vmcnt(0) barrier drain),
// global_load_lds width-16 staging, f32 accumulate.

typedef __attribute__((ext_vector_type(8))) short short8;
typedef __attribute__((ext_vector_type(4))) float f32x4;
typedef unsigned short u16;

#define SEQ 2048
#define NB 4

static __device__ __forceinline__ u16 f2bf(float f) {
    unsigned int u = __builtin_bit_cast(unsigned int, f);
    u += 0x7fffu + ((u >> 16) & 1u);   // RNE
    return (u16)(u >> 16);
}
static __device__ __forceinline__ float bf2f(u16 h) {
    unsigned int u = ((unsigned int)h) << 16;
    return __builtin_bit_cast(float, u);
}

// async global->LDS, 16 bytes/lane. LDS dest = wave-uniform base + lane*16.
static __device__ __forceinline__ void gld16(u16* l, const u16* g) {
    __builtin_amdgcn_global_load_lds(
        (__attribute__((address_space(1))) void*)(g),
        (__attribute__((address_space(3))) void*)(l),
        16, 0, 0);
}

// f32 -> bf16, 8 elems/thread.
__global__ __launch_bounds__(256) void cvt_bf16(const float* __restrict__ s,
                                                u16* __restrict__ d, long n) {
    long i = ((long)blockIdx.x * 256 + threadIdx.x) * 8;
    if (i >= n) return;
    f32x4 a = *(const f32x4*)(s + i);
    f32x4 b = *(const f32x4*)(s + i + 4);
    short8 o;
    o[0] = (short)f2bf(a.x); o[1] = (short)f2bf(a.y);
    o[2] = (short)f2bf(a.z); o[3] = (short)f2bf(a.w);
    o[4] = (short)f2bf(b.x); o[5] = (short)f2bf(b.y);
    o[6] = (short)f2bf(b.z); o[7] = (short)f2bf(b.w);
    *(short8*)(d + i) = o;
}

// f32 [R][C] -> bf16 [C][R] (transpose + convert), 32x32 LDS tiles.
__global__ __launch_bounds__(256) void transpose_cvt(const float* __restrict__ in,
                                                     u16* __restrict__ out,
                                                     int R, int C) {
    __shared__ float t[32][33];
    const int c0 = blockIdx.x * 32;
    const int r0 = blockIdx.y * 32;
    const int x = threadIdx.x & 31;
    const int y = (threadIdx.x >> 5) * 4;
    #pragma unroll
    for (int i = 0; i < 4; i++)
        t[y + i][x] = in[(long)(r0 + y + i) * C + c0 + x];
    __syncthreads();
    #pragma unroll
    for (int i = 0; i < 4; i++)
        out[(long)(c0 + y + i) * R + r0 + x] = f2bf(t[x][y + i]);
}

// V slice of qkv (per batch [2048 s][1024 d], row stride 3072, col offset 2048)
// -> vt [b][1024 d][2048 s]. bf16 32x32 tile transpose.
__global__ __launch_bounds__(256) void transpose_v(const u16* __restrict__ qkv,
                                                   u16* __restrict__ vt) {
    __shared__ u16 t[32][33];
    const int b = blockIdx.z;
    const int s0 = blockIdx.y * 32;
    const int d0 = blockIdx.x * 32;
    const int x = threadIdx.x & 31;
    const int y = (threadIdx.x >> 5) * 4;
    const u16* src = qkv + (long)b * SEQ * 3072 + 2048;
    u16* dst = vt + (long)b * 1024 * SEQ;
    #pragma unroll
    for (int i = 0; i < 4; i++)
        t[y + i][x] = src[(long)(s0 + y + i) * 3072 + d0 + x];
    __syncthreads();
    #pragma unroll
    for (int i = 0; i < 4; i++)
        dst[(long)(d0 + y + i) * SEQ + s0 + x] = t[x][y + i];
}

// bf16 MFMA GEMM. BM=BN=128, BK=64, 256 threads = 4 waves, each wave owns
// a 64x64 patch = 4x4 frags of mfma_f32_16x16x32_bf16 over 2 k-substeps.
// C[m][n] = sum_k A[m][k] * Bt[n][k]   (Bt = B^T, [N][K] row-major).
// Staging: 8 global_load_lds(16B)/thread/step into unpadded As/Bs[128][64]
// (lane-ordered chunks of 8 rows x 128 B). One barrier-pair per 64 K.
// EPI 0: bf16 out + optional f32 bias.
// EPI 1: bf16 out, *scale, mask==0 -> 1e-10.
// EPI 2: f32 out + f32 bias.
template<int EPI>
__global__ __launch_bounds__(256) void gemm128(
    const u16* __restrict__ Ap, long lda, long aBatch,
    const u16* __restrict__ Bp, long ldb, long bBatch,
    void* __restrict__ Cp, long ldc, long cBatch,
    const float* __restrict__ bias,
    const int* __restrict__ mask, long maskBatch,
    float scale, int K)
{
    __shared__ __attribute__((aligned(16))) u16 As[128 * 64];
    __shared__ __attribute__((aligned(16))) u16 Bs[128 * 64];

    const int tid = threadIdx.x;
    const int lane = tid & 63;
    const int wave = tid >> 6;
    const int b = blockIdx.z;
    const long m0 = (long)blockIdx.y * 128;
    const long n0 = (long)blockIdx.x * 128;

    const u16* A = Ap + (long)b * aBatch;
    const u16* B = Bp + (long)b * bBatch;

    const int wm = (wave >> 1) * 64;      // wave row offset in tile
    const int wn = (wave & 1) * 64;       // wave col offset in tile
    const int m16 = lane & 15;
    const int quad = lane >> 4;

    // staging coords: wave w covers rows [w*32, w*32+32) in 4 chunks of 8 rows
    const int srow = lane >> 3;           // 0..7 within a chunk
    const int skk = (lane & 7) * 8;       // u16 k-offset within a 64-wide row

    f32x4 acc[4][4];
    #pragma unroll
    for (int mi = 0; mi < 4; mi++)
        #pragma unroll
        for (int ni = 0; ni < 4; ni++)
            acc[mi][ni] = (f32x4){0.f, 0.f, 0.f, 0.f};

    for (int k0 = 0; k0 < K; k0 += 64) {
        #pragma unroll
        for (int c = 0; c < 4; c++) {
            const int r = wave * 32 + c * 8 + srow;
            gld16(As + (wave * 4 + c) * 512, A + (m0 + r) * lda + k0 + skk);
            gld16(Bs + (wave * 4 + c) * 512, B + (n0 + r) * ldb + k0 + skk);
        }
        __syncthreads();   // compiler emits s_waitcnt vmcnt(0) before s_barrier

        #pragma unroll
        for (int ks = 0; ks < 2; ks++) {
            short8 af[4], bf[4];
            #pragma unroll
            for (int i = 0; i < 4; i++) {
                af[i] = *(const short8*)&As[(wm + i * 16 + m16) * 64 + ks * 32 + quad * 8];
                bf[i] = *(const short8*)&Bs[(wn + i * 16 + m16) * 64 + ks * 32 + quad * 8];
            }
            #pragma unroll
            for (int mi = 0; mi < 4; mi++)
                #pragma unroll
                for (int ni = 0; ni < 4; ni++)
                    acc[mi][ni] = __builtin_amdgcn_mfma_f32_16x16x32_bf16(
                        af[mi], bf[ni], acc[mi][ni], 0, 0, 0);
        }
        __syncthreads();
    }

    // D mapping: col = lane&15 (+16*ni), row = quad*4 + r (+16*mi)
    const long row_base = m0 + wm + quad * 4;
    if (EPI == 0) {
        u16* C = (u16*)Cp + (long)b * cBatch;
        #pragma unroll
        for (int ni = 0; ni < 4; ni++) {
            const long col = n0 + wn + ni * 16 + m16;
            const float bv = bias ? bias[col] : 0.f;
            #pragma unroll
            for (int mi = 0; mi < 4; mi++)
                #pragma unroll
                for (int r = 0; r < 4; r++)
                    C[(row_base + mi * 16 + r) * ldc + col] = f2bf(acc[mi][ni][r] + bv);
        }
    } else if (EPI == 1) {
        u16* C = (u16*)Cp + (long)b * cBatch;
        const int* mb = mask + (long)b * maskBatch;
        #pragma unroll
        for (int ni = 0; ni < 4; ni++) {
            const long col = n0 + wn + ni * 16 + m16;
            #pragma unroll
            for (int mi = 0; mi < 4; mi++)
                #pragma unroll
                for (int r = 0; r < 4; r++) {
                    const long row = row_base + mi * 16 + r;
                    const float s = acc[mi][ni][r] * scale;
                    const int mv = mb[row * SEQ + col];
                    C[row * ldc + col] = f2bf((mv == 0) ? 1e-10f : s);
                }
        }
    } else {
        float* C = (float*)Cp + (long)b * cBatch;
        #pragma unroll
        for (int ni = 0; ni < 4; ni++) {
            const long col = n0 + wn + ni * 16 + m16;
            const float bv = bias ? bias[col] : 0.f;
            #pragma unroll
            for (int mi = 0; mi < 4; mi++)
                #pragma unroll
                for (int r = 0; r < 4; r++)
                    C[(row_base + mi * 16 + r) * ldc + col] = acc[mi][ni][r] + bv;
        }
    }
}

// in-place row softmax over 2048 bf16 (f32 math). 1 block (4 waves) per row.
__global__ __launch_bounds__(256) void softmax2048(u16* __restrict__ S) {
    u16* p = S + (long)blockIdx.x * SEQ;
    const int tid = threadIdx.x;

    short8 v = *(const short8*)(p + tid * 8);
    float f[8];
    #pragma unroll
    for (int j = 0; j < 8; j++) f[j] = bf2f((u16)v[j]);

    float m = f[0];
    #pragma unroll
    for (int j = 1; j < 8; j++) m = fmaxf(m, f[j]);
    #pragma unroll
    for (int i = 1; i < 64; i <<= 1) m = fmaxf(m, __shfl_xor(m, i));

    __shared__ float redm[4], reds[4];
    if ((tid & 63) == 0) redm[tid >> 6] = m;
    __syncthreads();
    m = fmaxf(fmaxf(redm[0], redm[1]), fmaxf(redm[2], redm[3]));

    float e[8], s = 0.f;
    #pragma unroll
    for (int j = 0; j < 8; j++) { e[j] = __expf(f[j] - m); s += e[j]; }
    #pragma unroll
    for (int i = 1; i < 64; i <<= 1) s += __shfl_xor(s, i);
    if ((tid & 63) == 0) reds[tid >> 6] = s;
    __syncthreads();
    s = reds[0] + reds[1] + reds[2] + reds[3];

    const float inv = 1.f / s;
    short8 o;
    #pragma unroll
    for (int j = 0; j < 8; j++) o[j] = (short)f2bf(e[j] * inv);
    *(short8*)(p + tid * 8) = o;
}

extern "C" void kernel_launch(void* const* d_in, const int* in_sizes, int n_in,
                              void* d_out, int out_size, void* d_ws, size_t ws_size,
                              hipStream_t stream) {
    const float* x    = (const float*)d_in[0];
    const int*   mask = (const int*)d_in[1];
    const float* Wqkv = (const float*)d_in[2];
    const float* bqkv = (const float*)d_in[3];
    const float* Wout = (const float*)d_in[4];
    const float* bout = (const float*)d_in[5];
    float* out = (float*)d_out;

    char* ws = (char*)d_ws;
    // ws layout, total 102,760,448 bytes:
    //   [0,        16777216) xh  bf16 [8192][1024]          (cvt -> K1)
    //   [16777216, 23068672) wqt bf16 [3072][1024]          (cvt -> K1)
    //   [0,        33554432) sc  bf16 [4][2048][2048]       (K2 -> K4; xh,wqt dead)
    //   [33554432, 35651584) wot bf16 [1024][1024]          (cvt -> K5)
    //   [35651584, 85983232) qkv bf16 [8192][3072]          (K1 -> K2)
    //   [35651584, 52428800) attn bf16 [8192][1024]         (K4 -> K5; qkv dead)
    //   [85983232,102760448) vt  bf16 [4][1024][2048]       (transpose_v -> K4)
    u16* xh   = (u16*)(ws + 0);
    u16* wqt  = (u16*)(ws + 16777216);
    u16* sc   = (u16*)(ws + 0);
    u16* wot  = (u16*)(ws + 33554432);
    u16* qkv  = (u16*)(ws + 35651584);
    u16* attn = (u16*)(ws + 35651584);
    u16* vt   = (u16*)(ws + 85983232);

    cvt_bf16<<<4096, 256, 0, stream>>>(x, xh, 8388608);
    transpose_cvt<<<dim3(96, 32), 256, 0, stream>>>(Wqkv, wqt, 1024, 3072);
    transpose_cvt<<<dim3(32, 32), 256, 0, stream>>>(Wout, wot, 1024, 1024);

    // K1: qkv = x @ Wqkv + bqkv   (M=8192, N=3072, K=1024), bf16 out
    gemm128<0><<<dim3(24, 64, 1), 256, 0, stream>>>(
        xh, 1024, 0, wqt, 1024, 0, qkv, 3072, 0, bqkv, nullptr, 0, 1.f, 1024);

    // V slice -> vt [b][d][s]
    transpose_v<<<dim3(32, 64, NB), 256, 0, stream>>>(qkv, vt);

    // K2: sc[b] = (Q[b] @ K[b]^T)/32, mask==0 -> 1e-10   (M=N=2048, K=1024)
    gemm128<1><<<dim3(16, 16, NB), 256, 0, stream>>>(
        qkv, 3072, (long)SEQ * 3072, qkv + 1024, 3072, (long)SEQ * 3072,
        sc, SEQ, (long)SEQ * SEQ, nullptr, mask, (long)SEQ * SEQ, 0.03125f, 1024);

    // K3: softmax rows (f32 math, bf16 storage)
    softmax2048<<<dim3(NB * SEQ), 256, 0, stream>>>(sc);

    // K4: attn[b] = P[b] @ V[b]   (M=2048, N=1024, K=2048), bf16 out
    gemm128<0><<<dim3(8, 16, NB), 256, 0, stream>>>(
        sc, SEQ, (long)SEQ * SEQ, vt, SEQ, (long)1024 * SEQ,
        attn, 1024, (long)SEQ * 1024, nullptr, nullptr, 0, 1.f, 2048);

    // K5: out = attn @ Wout + bout   (M=8192, N=1024, K=1024), f32 out
    gemm128<2><<<dim3(8, 64, 1), 256, 0, stream>>>(
        attn, 1024, 0, wot, 1024, 0, out, 1024, 0, bout, nullptr, 0, 1.f, 1024);
}

// Round 7
// 376.991 us; speedup vs baseline: 1.9615x; 1.0403x over previous
//
#include <hip/hip_runtime.h>

// Self-attention forward. Inputs f32: x[4,2048,1024], Wqkv[1024,3072],
// bqkv[3072], Wout[1024,1024], bout[1024]; mask[4,2048,2048] int32.
// Output f32 [4,2048,1024]. Internals: bf16 MFMA GEMMs (128x128 tile,
// BK=64), global_load_lds width-16 staging, f32 accumulate.
// Mask select moved out of K2's epilogue (scalar strided int loads in the
// MFMA kernel) into K3's softmax (coalesced uint4 streaming) — round-6
// counters showed K2 at 386 TF vs K1's 580 TF with the 67 MB mask read
// accounting for the FETCH delta.

typedef __attribute__((ext_vector_type(8))) short short8;
typedef __attribute__((ext_vector_type(4))) float f32x4;
typedef unsigned short u16;

#define SEQ 2048
#define NB 4

static __device__ __forceinline__ u16 f2bf(float f) {
    unsigned int u = __builtin_bit_cast(unsigned int, f);
    u += 0x7fffu + ((u >> 16) & 1u);   // RNE
    return (u16)(u >> 16);
}
static __device__ __forceinline__ float bf2f(u16 h) {
    unsigned int u = ((unsigned int)h) << 16;
    return __builtin_bit_cast(float, u);
}

// async global->LDS, 16 bytes/lane. LDS dest = wave-uniform base + lane*16.
static __device__ __forceinline__ void gld16(u16* l, const u16* g) {
    __builtin_amdgcn_global_load_lds(
        (__attribute__((address_space(1))) void*)(g),
        (__attribute__((address_space(3))) void*)(l),
        16, 0, 0);
}

// f32 -> bf16, 8 elems/thread.
__global__ __launch_bounds__(256) void cvt_bf16(const float* __restrict__ s,
                                                u16* __restrict__ d, long n) {
    long i = ((long)blockIdx.x * 256 + threadIdx.x) * 8;
    if (i >= n) return;
    f32x4 a = *(const f32x4*)(s + i);
    f32x4 b = *(const f32x4*)(s + i + 4);
    short8 o;
    o[0] = (short)f2bf(a.x); o[1] = (short)f2bf(a.y);
    o[2] = (short)f2bf(a.z); o[3] = (short)f2bf(a.w);
    o[4] = (short)f2bf(b.x); o[5] = (short)f2bf(b.y);
    o[6] = (short)f2bf(b.z); o[7] = (short)f2bf(b.w);
    *(short8*)(d + i) = o;
}

// f32 [R][C] -> bf16 [C][R] (transpose + convert), 32x32 LDS tiles.
__global__ __launch_bounds__(256) void transpose_cvt(const float* __restrict__ in,
                                                     u16* __restrict__ out,
                                                     int R, int C) {
    __shared__ float t[32][33];
    const int c0 = blockIdx.x * 32;
    const int r0 = blockIdx.y * 32;
    const int x = threadIdx.x & 31;
    const int y = (threadIdx.x >> 5) * 4;
    #pragma unroll
    for (int i = 0; i < 4; i++)
        t[y + i][x] = in[(long)(r0 + y + i) * C + c0 + x];
    __syncthreads();
    #pragma unroll
    for (int i = 0; i < 4; i++)
        out[(long)(c0 + y + i) * R + r0 + x] = f2bf(t[x][y + i]);
}

// V slice of qkv (per batch [2048 s][1024 d], row stride 3072, col offset 2048)
// -> vt [b][1024 d][2048 s]. bf16 32x32 tile transpose.
__global__ __launch_bounds__(256) void transpose_v(const u16* __restrict__ qkv,
                                                   u16* __restrict__ vt) {
    __shared__ u16 t[32][33];
    const int b = blockIdx.z;
    const int s0 = blockIdx.y * 32;
    const int d0 = blockIdx.x * 32;
    const int x = threadIdx.x & 31;
    const int y = (threadIdx.x >> 5) * 4;
    const u16* src = qkv + (long)b * SEQ * 3072 + 2048;
    u16* dst = vt + (long)b * 1024 * SEQ;
    #pragma unroll
    for (int i = 0; i < 4; i++)
        t[y + i][x] = src[(long)(s0 + y + i) * 3072 + d0 + x];
    __syncthreads();
    #pragma unroll
    for (int i = 0; i < 4; i++)
        dst[(long)(d0 + y + i) * SEQ + s0 + x] = t[x][y + i];
}

// bf16 MFMA GEMM. BM=BN=128, BK=64, 256 threads = 4 waves, each wave owns
// a 64x64 patch = 4x4 frags of mfma_f32_16x16x32_bf16 over 2 k-substeps.
// C[m][n] = sum_k A[m][k] * Bt[n][k]   (Bt = B^T, [N][K] row-major).
// Staging: 8 global_load_lds(16B)/thread/step into unpadded As/Bs[128][64]
// (lane-ordered chunks of 8 rows x 128 B). One barrier-pair per 64 K.
// EPI 0: bf16 out + optional f32 bias.
// EPI 1: bf16 out, *scale (no mask — applied in softmax).
// EPI 2: f32 out + f32 bias.
template<int EPI>
__global__ __launch_bounds__(256) void gemm128(
    const u16* __restrict__ Ap, long lda, long aBatch,
    const u16* __restrict__ Bp, long ldb, long bBatch,
    void* __restrict__ Cp, long ldc, long cBatch,
    const float* __restrict__ bias,
    float scale, int K)
{
    __shared__ __attribute__((aligned(16))) u16 As[128 * 64];
    __shared__ __attribute__((aligned(16))) u16 Bs[128 * 64];

    const int tid = threadIdx.x;
    const int lane = tid & 63;
    const int wave = tid >> 6;
    const int b = blockIdx.z;
    const long m0 = (long)blockIdx.y * 128;
    const long n0 = (long)blockIdx.x * 128;

    const u16* A = Ap + (long)b * aBatch;
    const u16* B = Bp + (long)b * bBatch;

    const int wm = (wave >> 1) * 64;      // wave row offset in tile
    const int wn = (wave & 1) * 64;       // wave col offset in tile
    const int m16 = lane & 15;
    const int quad = lane >> 4;

    // staging coords: wave w covers rows [w*32, w*32+32) in 4 chunks of 8 rows
    const int srow = lane >> 3;           // 0..7 within a chunk
    const int skk = (lane & 7) * 8;       // u16 k-offset within a 64-wide row

    f32x4 acc[4][4];
    #pragma unroll
    for (int mi = 0; mi < 4; mi++)
        #pragma unroll
        for (int ni = 0; ni < 4; ni++)
            acc[mi][ni] = (f32x4){0.f, 0.f, 0.f, 0.f};

    for (int k0 = 0; k0 < K; k0 += 64) {
        #pragma unroll
        for (int c = 0; c < 4; c++) {
            const int r = wave * 32 + c * 8 + srow;
            gld16(As + (wave * 4 + c) * 512, A + (m0 + r) * lda + k0 + skk);
            gld16(Bs + (wave * 4 + c) * 512, B + (n0 + r) * ldb + k0 + skk);
        }
        __syncthreads();

        #pragma unroll
        for (int ks = 0; ks < 2; ks++) {
            short8 af[4], bf[4];
            #pragma unroll
            for (int i = 0; i < 4; i++) {
                af[i] = *(const short8*)&As[(wm + i * 16 + m16) * 64 + ks * 32 + quad * 8];
                bf[i] = *(const short8*)&Bs[(wn + i * 16 + m16) * 64 + ks * 32 + quad * 8];
            }
            #pragma unroll
            for (int mi = 0; mi < 4; mi++)
                #pragma unroll
                for (int ni = 0; ni < 4; ni++)
                    acc[mi][ni] = __builtin_amdgcn_mfma_f32_16x16x32_bf16(
                        af[mi], bf[ni], acc[mi][ni], 0, 0, 0);
        }
        __syncthreads();
    }

    // D mapping: col = lane&15 (+16*ni), row = quad*4 + r (+16*mi)
    const long row_base = m0 + wm + quad * 4;
    if (EPI == 0) {
        u16* C = (u16*)Cp + (long)b * cBatch;
        #pragma unroll
        for (int ni = 0; ni < 4; ni++) {
            const long col = n0 + wn + ni * 16 + m16;
            const float bv = bias ? bias[col] : 0.f;
            #pragma unroll
            for (int mi = 0; mi < 4; mi++)
                #pragma unroll
                for (int r = 0; r < 4; r++)
                    C[(row_base + mi * 16 + r) * ldc + col] = f2bf(acc[mi][ni][r] + bv);
        }
    } else if (EPI == 1) {
        u16* C = (u16*)Cp + (long)b * cBatch;
        #pragma unroll
        for (int ni = 0; ni < 4; ni++) {
            const long col = n0 + wn + ni * 16 + m16;
            #pragma unroll
            for (int mi = 0; mi < 4; mi++)
                #pragma unroll
                for (int r = 0; r < 4; r++)
                    C[(row_base + mi * 16 + r) * ldc + col] = f2bf(acc[mi][ni][r] * scale);
        }
    } else {
        float* C = (float*)Cp + (long)b * cBatch;
        #pragma unroll
        for (int ni = 0; ni < 4; ni++) {
            const long col = n0 + wn + ni * 16 + m16;
            const float bv = bias ? bias[col] : 0.f;
            #pragma unroll
            for (int mi = 0; mi < 4; mi++)
                #pragma unroll
                for (int r = 0; r < 4; r++)
                    C[(row_base + mi * 16 + r) * ldc + col] = acc[mi][ni][r] + bv;
        }
    }
}

// in-place masked row softmax over 2048 bf16 (f32 math). 1 block per row.
// mask==0 -> score := 1e-10 (applied here in f32; coalesced uint4 reads).
__global__ __launch_bounds__(256) void softmax2048(u16* __restrict__ S,
                                                   const int* __restrict__ mask) {
    const long row = blockIdx.x;
    u16* p = S + row * SEQ;
    const int* mrow = mask + row * SEQ;   // mask rows match sc rows (b*2048+q)
    const int tid = threadIdx.x;

    short8 v = *(const short8*)(p + tid * 8);
    uint4 mw0 = *(const uint4*)(mrow + tid * 8);
    uint4 mw1 = *(const uint4*)(mrow + tid * 8 + 4);
    const unsigned int* mwv = (const unsigned int*)&mw0;

    float f[8];
    #pragma unroll
    for (int j = 0; j < 8; j++) {
        const unsigned int mv = (j < 4) ? mwv[j] : ((const unsigned int*)&mw1)[j - 4];
        f[j] = (mv == 0u) ? 1e-10f : bf2f((u16)v[j]);
    }

    float m = f[0];
    #pragma unroll
    for (int j = 1; j < 8; j++) m = fmaxf(m, f[j]);
    #pragma unroll
    for (int i = 1; i < 64; i <<= 1) m = fmaxf(m, __shfl_xor(m, i));

    __shared__ float redm[4], reds[4];
    if ((tid & 63) == 0) redm[tid >> 6] = m;
    __syncthreads();
    m = fmaxf(fmaxf(redm[0], redm[1]), fmaxf(redm[2], redm[3]));

    float e[8], s = 0.f;
    #pragma unroll
    for (int j = 0; j < 8; j++) { e[j] = __expf(f[j] - m); s += e[j]; }
    #pragma unroll
    for (int i = 1; i < 64; i <<= 1) s += __shfl_xor(s, i);
    if ((tid & 63) == 0) reds[tid >> 6] = s;
    __syncthreads();
    s = reds[0] + reds[1] + reds[2] + reds[3];

    const float inv = 1.f / s;
    short8 o;
    #pragma unroll
    for (int j = 0; j < 8; j++) o[j] = (short)f2bf(e[j] * inv);
    *(short8*)(p + tid * 8) = o;
}

extern "C" void kernel_launch(void* const* d_in, const int* in_sizes, int n_in,
                              void* d_out, int out_size, void* d_ws, size_t ws_size,
                              hipStream_t stream) {
    const float* x    = (const float*)d_in[0];
    const int*   mask = (const int*)d_in[1];
    const float* Wqkv = (const float*)d_in[2];
    const float* bqkv = (const float*)d_in[3];
    const float* Wout = (const float*)d_in[4];
    const float* bout = (const float*)d_in[5];
    float* out = (float*)d_out;

    char* ws = (char*)d_ws;
    // ws layout, total 102,760,448 bytes:
    //   [0,        16777216) xh  bf16 [8192][1024]          (cvt -> K1)
    //   [16777216, 23068672) wqt bf16 [3072][1024]          (cvt -> K1)
    //   [0,        33554432) sc  bf16 [4][2048][2048]       (K2 -> K4; xh,wqt dead)
    //   [33554432, 35651584) wot bf16 [1024][1024]          (cvt -> K5)
    //   [35651584, 85983232) qkv bf16 [8192][3072]          (K1 -> K2)
    //   [35651584, 52428800) attn bf16 [8192][1024]         (K4 -> K5; qkv dead)
    //   [85983232,102760448) vt  bf16 [4][1024][2048]       (transpose_v -> K4)
    u16* xh   = (u16*)(ws + 0);
    u16* wqt  = (u16*)(ws + 16777216);
    u16* sc   = (u16*)(ws + 0);
    u16* wot  = (u16*)(ws + 33554432);
    u16* qkv  = (u16*)(ws + 35651584);
    u16* attn = (u16*)(ws + 35651584);
    u16* vt   = (u16*)(ws + 85983232);

    cvt_bf16<<<4096, 256, 0, stream>>>(x, xh, 8388608);
    transpose_cvt<<<dim3(96, 32), 256, 0, stream>>>(Wqkv, wqt, 1024, 3072);
    transpose_cvt<<<dim3(32, 32), 256, 0, stream>>>(Wout, wot, 1024, 1024);

    // K1: qkv = x @ Wqkv + bqkv   (M=8192, N=3072, K=1024), bf16 out
    gemm128<0><<<dim3(24, 64, 1), 256, 0, stream>>>(
        xh, 1024, 0, wqt, 1024, 0, qkv, 3072, 0, bqkv, 1.f, 1024);

    // V slice -> vt [b][d][s]
    transpose_v<<<dim3(32, 64, NB), 256, 0, stream>>>(qkv, vt);

    // K2: sc[b] = (Q[b] @ K[b]^T)/32   (M=N=2048, K=1024), bf16 out
    gemm128<1><<<dim3(16, 16, NB), 256, 0, stream>>>(
        qkv, 3072, (long)SEQ * 3072, qkv + 1024, 3072, (long)SEQ * 3072,
        sc, SEQ, (long)SEQ * SEQ, nullptr, 0.03125f, 1024);

    // K3: masked softmax rows (mask==0 -> 1e-10, f32 math, bf16 storage)
    softmax2048<<<dim3(NB * SEQ), 256, 0, stream>>>(sc, mask);

    // K4: attn[b] = P[b] @ V[b]   (M=2048, N=1024, K=2048), bf16 out
    gemm128<0><<<dim3(8, 16, NB), 256, 0, stream>>>(
        sc, SEQ, (long)SEQ * SEQ, vt, SEQ, (long)1024 * SEQ,
        attn, 1024, (long)SEQ * 1024, nullptr, 1.f, 2048);

    // K5: out = attn @ Wout + bout   (M=8192, N=1024, K=1024), f32 out
    gemm128<2><<<dim3(8, 64, 1), 256, 0, stream>>>(
        attn, 1024, 0, wot, 1024, 0, out, 1024, 0, bout, 1.f, 1024);
}